// Round 6
// baseline (211.491 us; speedup 1.0000x reference)
//
#include <hip/hip_runtime.h>
#include <stdint.h>

// Problem constants
#define TIN   2048
#define TCOND 1024
#define SEQ   3072            // TIN + TCOND
#define NB    2
#define NH    16
#define DM    1024
#define HDIM  64
#define WIN   512
#define MROWS (NB*SEQ)        // 6144
#define NQKV  (3*DM)          // 3072

typedef float  floatx4 __attribute__((ext_vector_type(4)));
typedef short  bf16x8  __attribute__((ext_vector_type(8)));

__device__ __forceinline__ unsigned short f2bf(float f) {
    unsigned int u = __float_as_uint(f);
    u += 0x7fffu + ((u >> 16) & 1u);       // round-to-nearest-even
    return (unsigned short)(u >> 16);
}

__device__ __forceinline__ unsigned int pack2bf(float a, float b) {
    return (unsigned int)f2bf(a) | ((unsigned int)f2bf(b) << 16);
}

__device__ __forceinline__ void gl2lds16(const void* g, void* l) {
    // async global->LDS, 16B per lane; LDS dest = wave-uniform base + lane*16
    __builtin_amdgcn_global_load_lds(
        (const __attribute__((address_space(1))) unsigned int*)g,
        (__attribute__((address_space(3))) unsigned int*)l, 16, 0, 0);
}

// ---------------------------------------------------------------------------
// Combined cast/pack kernel: blocks [0,6144) pack x|cond -> bf16 inp,
// blocks [6144,10240) cast weights -> bf16.
// ---------------------------------------------------------------------------
__global__ __launch_bounds__(256) void prep(const float* __restrict__ x,
                                            const float* __restrict__ cond,
                                            const float* __restrict__ w_in,
                                            const float* __restrict__ w_out,
                                            unsigned short* __restrict__ inp,
                                            unsigned short* __restrict__ wi_bf,
                                            unsigned short* __restrict__ wo_bf) {
    if (blockIdx.x < 6144) {
        int v = blockIdx.x * 256 + threadIdx.x;
        int m  = v >> 8;
        int d4 = v & 255;
        int bb = (m >= SEQ) ? 1 : 0;
        int s  = m - bb * SEQ;
        const float* src = (s < TIN)
            ? x    + ((size_t)(bb * TIN   + s)        ) * DM + d4 * 4
            : cond + ((size_t)(bb * TCOND + (s - TIN))) * DM + d4 * 4;
        float4 f = *(const float4*)src;
        ushort4 u;
        u.x = f2bf(f.x); u.y = f2bf(f.y); u.z = f2bf(f.z); u.w = f2bf(f.w);
        *(ushort4*)(inp + (size_t)v * 4) = u;
    } else {
        int v = (blockIdx.x - 6144) * 256 + threadIdx.x;   // 0..1048575
        const float* src; unsigned short* dst; int idx;
        if (v < 786432) { src = w_in;  dst = wi_bf; idx = v; }
        else            { src = w_out; dst = wo_bf; idx = v - 786432; }
        float4 f = *(const float4*)(src + (size_t)idx * 4);
        ushort4 u;
        u.x = f2bf(f.x); u.y = f2bf(f.y); u.z = f2bf(f.z); u.w = f2bf(f.w);
        *(ushort4*)(dst + (size_t)idx * 4) = u;
    }
}

// ---------------------------------------------------------------------------
// QKV GEMM: C = A(6144,1024) * Wi(3072,1024)^T, bf16 in, fp32 acc.
// 256 thr = 4 waves (2m x 2n), tile 128x128, wave tile 64x64, BK=32, dbuf.
// Grid 24x48 = 1152 blocks -> 4+ blocks/CU with (256,4): 16 waves/CU of
// independent blocks (de-correlated barriers). Unroll-2 hoists it&1 addrs.
// Epilogue: bias, Q*=0.125, scatter to q/k (LDS transpose) and vt layouts.
// ---------------------------------------------------------------------------
__global__ __launch_bounds__(256, 4) void gemm_qkv(
        const unsigned short* __restrict__ A, const unsigned short* __restrict__ Bt,
        const float* __restrict__ bias,
        unsigned short* __restrict__ q_ws, unsigned short* __restrict__ k_ws,
        unsigned short* __restrict__ vt_ws) {
    __shared__ unsigned short smem[2 * 8192];   // 2 bufs x (As 4096 | Bs 4096) = 32 KB
    const int K = 1024;
    const int tid  = threadIdx.x;
    const int wave = tid >> 6, lane = tid & 63;
    const int quad = lane >> 4, c16 = lane & 15;
    const int wr = wave >> 1, wc = wave & 1;
    const int m0 = blockIdx.y * 128, n0 = blockIdx.x * 128;

    const unsigned short* gA[2];
    const unsigned short* gB[2];
    int ldst[2];
#pragma unroll
    for (int i = 0; i < 2; i++) {
        int flat = i * 256 + tid;
        int pr = flat >> 2, cp = flat & 3;
        int gc = cp ^ ((pr >> 1) & 3);
        gA[i] = A  + (size_t)(m0 + pr) * K + (gc << 3);
        gB[i] = Bt + (size_t)(n0 + pr) * K + (gc << 3);
        ldst[i] = (i * 256 + wave * 64) * 8;
    }

    floatx4 acc[4][4];
#pragma unroll
    for (int i = 0; i < 4; i++)
#pragma unroll
        for (int j = 0; j < 4; j++) acc[i][j] = (floatx4){0.f, 0.f, 0.f, 0.f};

    // prologue: stage tile 0 into buf 0
#pragma unroll
    for (int i = 0; i < 2; i++) {
        gl2lds16(gA[i], &smem[ldst[i]]);
        gl2lds16(gB[i], &smem[4096 + ldst[i]]);
    }

#pragma unroll 2
    for (int it = 0; it < 32; ++it) {
        __syncthreads();                          // drains prev DMA (covered by compute)
        if (it + 1 < 32) {
            int bo = ((it + 1) & 1) * 8192;
            int k0 = (it + 1) << 5;
#pragma unroll
            for (int i = 0; i < 2; i++) {
                gl2lds16(gA[i] + k0, &smem[bo + ldst[i]]);
                gl2lds16(gB[i] + k0, &smem[bo + 4096 + ldst[i]]);
            }
        }
        const unsigned short* As = &smem[(it & 1) * 8192];
        const unsigned short* Bs = As + 4096;
        bf16x8 af[4], bfr[4];
#pragma unroll
        for (int t = 0; t < 4; t++) {
            int ra = wr * 64 + t * 16 + c16;
            int rb = wc * 64 + t * 16 + c16;
            af[t]  = *(const bf16x8*)&As[ra * 32 + ((quad ^ ((ra >> 1) & 3)) << 3)];
            bfr[t] = *(const bf16x8*)&Bs[rb * 32 + ((quad ^ ((rb >> 1) & 3)) << 3)];
        }
#pragma unroll
        for (int mt = 0; mt < 4; mt++)
#pragma unroll
            for (int nt = 0; nt < 4; nt++)
                acc[mt][nt] = __builtin_amdgcn_mfma_f32_16x16x32_bf16(
                    af[mt], bfr[nt], acc[mt][nt], 0, 0, 0);
    }

    // Epilogue. C/D layout: col = lane&15, row = quad*4 + r  (m89/m91)
    const int which = n0 >> 10;          // 0=q 1=k 2=v, uniform per block
    const int h0 = (n0 >> 6) & 15;       // first of the 2 heads this block covers
    if (which == 2) {
        // vt[(bh*64+hd)][s]: lane's 4 acc values are 4 consecutive s -> uint2 stores
#pragma unroll
        for (int mt = 0; mt < 4; mt++) {
            int m = m0 + wr * 64 + mt * 16 + quad * 4;
            int bb = (m >= SEQ) ? 1 : 0;
            int s = m - bb * SEQ;
#pragma unroll
            for (int nt = 0; nt < 4; nt++) {
                int gn = n0 + wc * 64 + nt * 16 + c16;
                float bi = bias[gn];
                int h = (gn >> 6) & 15, hd = gn & 63;
                uint2 w;
                w.x = pack2bf(acc[mt][nt][0] + bi, acc[mt][nt][1] + bi);
                w.y = pack2bf(acc[mt][nt][2] + bi, acc[mt][nt][3] + bi);
                *(uint2*)&vt_ws[((size_t)(bb * NH + h) * HDIM + hd) * SEQ + s] = w;
            }
        }
    } else {
        // q/k[(bh*S+s)*64+hd]: LDS transpose -> coalesced 16B row stores
        unsigned short* dstb = (which == 0) ? q_ws : k_ws;
        const float qs = (which == 0) ? 0.125f : 1.0f;
#pragma unroll
        for (int mt = 0; mt < 4; mt++) {
            __syncthreads();
#pragma unroll
            for (int nt = 0; nt < 4; nt++) {
                int col = wc * 64 + nt * 16 + c16;
                float bi = bias[n0 + col];
#pragma unroll
                for (int r = 0; r < 4; r++)
                    smem[(wr * 16 + quad * 4 + r) * 136 + col] =
                        f2bf((acc[mt][nt][r] + bi) * qs);
            }
            __syncthreads();
#pragma unroll
            for (int p = 0; p < 2; p++) {
                int flat = p * 256 + tid;
                int row = flat >> 4, seg = flat & 15;
                bf16x8 v = *(const bf16x8*)&smem[row * 136 + seg * 8];
                int m = m0 + (row >> 4) * 64 + mt * 16 + (row & 15);
                int bb = (m >= SEQ) ? 1 : 0;
                int s = m - bb * SEQ;
                int h = h0 + (seg >> 3);
                *(bf16x8*)&dstb[((size_t)(bb * NH + h) * SEQ + s) * HDIM + (seg & 7) * 8] = v;
            }
        }
    }
}

// ---------------------------------------------------------------------------
// Output GEMM: out = O(6144,1024) * Wo(1024,1024)^T + b, fp32 out.
// Tile 64x128 (wave tile 32x64), 256 thr, BK=32 dbuf. Grid 8x96 = 768 blocks
// -> 3-4 blocks/CU (12-16 waves/CU) vs the old 384-block 6-waves/CU config.
// ---------------------------------------------------------------------------
__global__ __launch_bounds__(256, 4) void gemm_out(
        const unsigned short* __restrict__ A, const unsigned short* __restrict__ Bt,
        const float* __restrict__ bias, float* __restrict__ outp) {
    __shared__ unsigned short smem[2 * 6144];   // 2 bufs x (As 2048 | Bs 4096) = 24 KB
    const int K = 1024;
    const int tid  = threadIdx.x;
    const int wave = tid >> 6, lane = tid & 63;
    const int quad = lane >> 4, c16 = lane & 15;
    const int wr = wave >> 1, wc = wave & 1;     // 2m x 2n wave grid
    const int m0 = blockIdx.y * 64, n0 = blockIdx.x * 128;

    // staging: A 64x32 (1 inst), B 128x32 (2 insts)
    const unsigned short* gA;
    int ldstA;
    {
        int pr = tid >> 2, cp = tid & 3;
        int gc = cp ^ ((pr >> 1) & 3);
        gA = A + (size_t)(m0 + pr) * K + (gc << 3);
        ldstA = wave * 64 * 8;
    }
    const unsigned short* gB[2];
    int ldstB[2];
#pragma unroll
    for (int i = 0; i < 2; i++) {
        int flat = i * 256 + tid;
        int pr = flat >> 2, cp = flat & 3;
        int gc = cp ^ ((pr >> 1) & 3);
        gB[i] = Bt + (size_t)(n0 + pr) * K + (gc << 3);
        ldstB[i] = 2048 + (i * 256 + wave * 64) * 8;
    }

    floatx4 acc[2][4];
#pragma unroll
    for (int i = 0; i < 2; i++)
#pragma unroll
        for (int j = 0; j < 4; j++) acc[i][j] = (floatx4){0.f, 0.f, 0.f, 0.f};

    // prologue
    gl2lds16(gA, &smem[ldstA]);
    gl2lds16(gB[0], &smem[ldstB[0]]);
    gl2lds16(gB[1], &smem[ldstB[1]]);

#pragma unroll 2
    for (int it = 0; it < 32; ++it) {
        __syncthreads();
        if (it + 1 < 32) {
            int bo = ((it + 1) & 1) * 6144;
            int k0 = (it + 1) << 5;
            gl2lds16(gA + k0, &smem[bo + ldstA]);
            gl2lds16(gB[0] + k0, &smem[bo + ldstB[0]]);
            gl2lds16(gB[1] + k0, &smem[bo + ldstB[1]]);
        }
        const unsigned short* As = &smem[(it & 1) * 6144];
        const unsigned short* Bs = As + 2048;
        bf16x8 af[2], bfr[4];
#pragma unroll
        for (int t = 0; t < 2; t++) {
            int ra = wr * 32 + t * 16 + c16;
            af[t] = *(const bf16x8*)&As[ra * 32 + ((quad ^ ((ra >> 1) & 3)) << 3)];
        }
#pragma unroll
        for (int t = 0; t < 4; t++) {
            int rb = wc * 64 + t * 16 + c16;
            bfr[t] = *(const bf16x8*)&Bs[rb * 32 + ((quad ^ ((rb >> 1) & 3)) << 3)];
        }
#pragma unroll
        for (int mt = 0; mt < 2; mt++)
#pragma unroll
            for (int nt = 0; nt < 4; nt++)
                acc[mt][nt] = __builtin_amdgcn_mfma_f32_16x16x32_bf16(
                    af[mt], bfr[nt], acc[mt][nt], 0, 0, 0);
    }

    // fp32 out via LDS transpose -> coalesced float4 stores
    float* smf = (float*)smem;           // 32 x 132 floats (16.9 KB of 24 KB)
#pragma unroll
    for (int mt = 0; mt < 2; mt++) {
        __syncthreads();
#pragma unroll
        for (int nt = 0; nt < 4; nt++) {
            int col = wc * 64 + nt * 16 + c16;
            float bi = bias[n0 + col];
#pragma unroll
            for (int r = 0; r < 4; r++)
                smf[(wr * 16 + quad * 4 + r) * 132 + col] = acc[mt][nt][r] + bi;
        }
        __syncthreads();
#pragma unroll
        for (int p = 0; p < 4; p++) {
            int flat = p * 256 + tid;
            int row = flat >> 5, seg = flat & 31;
            float4 v = *(const float4*)&smf[row * 132 + seg * 4];
            int m = m0 + (row >> 4) * 32 + mt * 16 + (row & 15);
            *(float4*)&outp[(size_t)m * DM + n0 + seg * 4] = v;
        }
    }
}

// ---------------------------------------------------------------------------
// Flash attention: S^T = K*Q^T, 64-key double-buffered chunks (32 KB LDS),
// 2 q-tiles/wave (128 q/block). Grid 24x16x2 = 768 blocks -> 3 blocks/CU,
// 12 waves/CU (vs 8 before). 16 chunks of 64 keys; key-permuted + swizzled.
// Q,K: (B,H,S,64) bf16 (Q pre-scaled by 1/8). Vt: (B,H,64,S) bf16. O: (B,S,D) bf16.
// ---------------------------------------------------------------------------
__global__ __launch_bounds__(256, 4) void attn_kernel(
        const unsigned short* __restrict__ Q, const unsigned short* __restrict__ K,
        const unsigned short* __restrict__ Vt, const int* __restrict__ end_inds,
        unsigned short* __restrict__ O) {
    __shared__ unsigned short smem[2 * 8192];   // 2 bufs x (Ks 4096 | Vs 4096) = 32 KB

    const int tid  = threadIdx.x;
    const int wave = tid >> 6, lane = tid & 63;
    const int quad = lane >> 4, c16 = lane & 15;
    const int qt = blockIdx.x, h = blockIdx.y, b = blockIdx.z;
    const int bh = b * NH + h;
    const int e  = end_inds[b];
    const int qbase = qt * 128 + wave * 32;

    const unsigned short* Qp = Q + ((size_t)bh * SEQ + qbase) * HDIM;
    bf16x8 bq[2][2];
#pragma unroll
    for (int qi = 0; qi < 2; qi++)
#pragma unroll
        for (int kk = 0; kk < 2; kk++)
            bq[qi][kk] = *(const bf16x8*)&Qp[(qi * 16 + c16) * HDIM + kk * 32 + quad * 8];

    float l_run[2] = {0.f, 0.f};
    floatx4 accO[2][4];
#pragma unroll
    for (int qi = 0; qi < 2; qi++)
#pragma unroll
        for (int t = 0; t < 4; t++) accO[qi][t] = (floatx4){0.f, 0.f, 0.f, 0.f};

    // staging geometry: K chunk 64 rows (key-permuted) x 64 hd, 2 DMA insts;
    // V chunk 64 hd-rows x 64 keys, 2 DMA insts. Both XOR-swizzled (8 chunks/row).
    int k_src[2], v_src[2], dst_off[2];
#pragma unroll
    for (int i = 0; i < 2; i++) {
        int flat = i * 256 + tid;
        int pr = flat >> 3, cp = flat & 7;           // pr 0..63
        int m5 = pr & 31;
        int kl = (pr & ~31) + (((m5 & 15) >> 2) << 3) + (m5 & 3) + ((m5 >> 4) << 2);
        k_src[i] = kl * HDIM + ((cp ^ (pr & 7)) << 3);
        v_src[i] = pr * SEQ + ((cp ^ (pr & 7)) << 3);
        dst_off[i] = (i * 256 + wave * 64) * 8;
    }

    const unsigned short* Kbase = K  + (size_t)bh * SEQ * HDIM;
    const unsigned short* Vbase = Vt + (size_t)bh * HDIM * SEQ;

    // prologue: stage chunk 0 into buf 0
    {
        int s0 = e - WIN;
#pragma unroll
        for (int i = 0; i < 2; i++) {
            gl2lds16(Kbase + (size_t)s0 * HDIM + k_src[i], &smem[dst_off[i]]);
            gl2lds16(Vbase + s0 + v_src[i], &smem[4096 + dst_off[i]]);
        }
    }

    for (int ch = 0; ch < 16; ch++) {
        __syncthreads();
        if (ch + 1 < 16) {
            int bo = ((ch + 1) & 1) * 8192;
            int cn = ch + 1;
            int s0 = (cn < 8) ? (e - WIN + cn * 64) : (TIN + e - WIN + (cn - 8) * 64);
#pragma unroll
            for (int i = 0; i < 2; i++) {
                gl2lds16(Kbase + (size_t)s0 * HDIM + k_src[i], &smem[bo + dst_off[i]]);
                gl2lds16(Vbase + s0 + v_src[i], &smem[bo + 4096 + dst_off[i]]);
            }
        }
        const unsigned short* Ks = &smem[(ch & 1) * 8192];
        const unsigned short* Vs = Ks + 4096;

#pragma unroll
        for (int u = 0; u < 2; u++) {               // 32-key blocks
            unsigned int pb[2][4];                  // P^T B-frags (8 bf16 per qi)
#pragma unroll
            for (int sub = 0; sub < 2; sub++) {
                int prow = u * 32 + sub * 16 + c16;
                int sw = c16 & 7;
                bf16x8 ka0 = *(const bf16x8*)&Ks[prow * 64 + (( quad      ^ sw) << 3)];
                bf16x8 ka1 = *(const bf16x8*)&Ks[prow * 64 + (((quad + 4) ^ sw) << 3)];
#pragma unroll
                for (int qi = 0; qi < 2; qi++) {
                    floatx4 z = (floatx4){0.f, 0.f, 0.f, 0.f};
                    z = __builtin_amdgcn_mfma_f32_16x16x32_bf16(ka0, bq[qi][0], z, 0, 0, 0);
                    z = __builtin_amdgcn_mfma_f32_16x16x32_bf16(ka1, bq[qi][1], z, 0, 0, 0);
                    float p0 = __expf(z[0]), p1 = __expf(z[1]);
                    float p2 = __expf(z[2]), p3 = __expf(z[3]);
                    l_run[qi] += (p0 + p1) + (p2 + p3);
                    pb[qi][sub * 2 + 0] = pack2bf(p0, p1);
                    pb[qi][sub * 2 + 1] = pack2bf(p2, p3);
                }
            }
#pragma unroll
            for (int t = 0; t < 4; t++) {
                int vrow = t * 16 + c16;
                bf16x8 va = *(const bf16x8*)&Vs[vrow * 64 +
                                                (((u * 4 + quad) ^ (vrow & 7)) << 3)];
#pragma unroll
                for (int qi = 0; qi < 2; qi++)
                    accO[qi][t] = __builtin_amdgcn_mfma_f32_16x16x32_bf16(
                        va, *(const bf16x8*)&pb[qi][0], accO[qi][t], 0, 0, 0);
            }
        }
    }

    float inv[2];
#pragma unroll
    for (int qi = 0; qi < 2; qi++) {
        float l = l_run[qi];
        l += __shfl_xor(l, 16, 64);
        l += __shfl_xor(l, 32, 64);
        inv[qi] = 1.f / l;
    }

    // epilogue: transpose O^T -> O via LDS (padded stride 72), coalesced stores
    __syncthreads();
    unsigned short* Os = smem + wave * (32 * 72);
#pragma unroll
    for (int qi = 0; qi < 2; qi++)
#pragma unroll
        for (int t = 0; t < 4; t++) {
            uint2 w;
            w.x = pack2bf(accO[qi][t][0] * inv[qi], accO[qi][t][1] * inv[qi]);
            w.y = pack2bf(accO[qi][t][2] * inv[qi], accO[qi][t][3] * inv[qi]);
            *(uint2*)&Os[(qi * 16 + c16) * 72 + t * 16 + quad * 4] = w;
        }
    __syncthreads();
#pragma unroll
    for (int pass = 0; pass < 4; pass++) {
        int rq = pass * 8 + (lane >> 3);
        int part = lane & 7;
        bf16x8 v = *(const bf16x8*)&Os[rq * 72 + part * 8];
        int s = qbase + rq;
        *(bf16x8*)&O[((size_t)b * SEQ + s) * DM + h * HDIM + part * 8] = v;
    }
}

// ---------------------------------------------------------------------------
extern "C" void kernel_launch(void* const* d_in, const int* in_sizes, int n_in,
                              void* d_out, int out_size, void* d_ws, size_t ws_size,
                              hipStream_t stream) {
    const float* x      = (const float*)d_in[0];
    const float* cond   = (const float*)d_in[1];
    const int*   e_inds = (const int*)d_in[2];
    const float* w_in   = (const float*)d_in[3];
    const float* b_in   = (const float*)d_in[4];
    const float* w_out  = (const float*)d_in[5];
    const float* b_out  = (const float*)d_in[6];
    float* out = (float*)d_out;

    char* ws = (char*)d_ws;
    unsigned short* inp_bf = (unsigned short*)(ws);
    unsigned short* wi_bf  = (unsigned short*)(ws + 12582912);
    unsigned short* wo_bf  = (unsigned short*)(ws + 18874368);
    unsigned short* q_ws   = (unsigned short*)(ws + 20971520);
    unsigned short* k_ws   = (unsigned short*)(ws + 33554432);
    unsigned short* vt_ws  = (unsigned short*)(ws + 46137344);   // ends at 58720256
    unsigned short* o_bf   = inp_bf;   // alias: inp dead after GEMM1

    prep<<<10240, 256, 0, stream>>>(x, cond, w_in, w_out, inp_bf, wi_bf, wo_bf);
    gemm_qkv<<<dim3(NQKV / 128, MROWS / 128), 256, 0, stream>>>(
        inp_bf, wi_bf, b_in, q_ws, k_ws, vt_ws);
    attn_kernel<<<dim3(SEQ / 128, NH, NB), 256, 0, stream>>>(
        q_ws, k_ws, vt_ws, e_inds, o_bf);
    gemm_out<<<dim3(DM / 128, MROWS / 64), 256, 0, stream>>>(
        o_bf, wo_bf, b_out, out);
}

// Round 7
// 189.227 us; speedup vs baseline: 1.1177x; 1.1177x over previous
//
#include <hip/hip_runtime.h>
#include <stdint.h>

// Problem constants
#define TIN   2048
#define TCOND 1024
#define SEQ   3072            // TIN + TCOND
#define NB    2
#define NH    16
#define DM    1024
#define HDIM  64
#define WIN   512
#define KW    1024            // window keys per batch (2 segments x 512)
#define MROWS (NB*SEQ)        // 6144

typedef float  floatx4 __attribute__((ext_vector_type(4)));
typedef short  bf16x8  __attribute__((ext_vector_type(8)));

__device__ __forceinline__ unsigned short f2bf(float f) {
    unsigned int u = __float_as_uint(f);
    u += 0x7fffu + ((u >> 16) & 1u);       // round-to-nearest-even
    return (unsigned short)(u >> 16);
}

__device__ __forceinline__ unsigned int pack2bf(float a, float b) {
    return (unsigned int)f2bf(a) | ((unsigned int)f2bf(b) << 16);
}

__device__ __forceinline__ void gl2lds16(const void* g, void* l) {
    // async global->LDS, 16B per lane; LDS dest = wave-uniform base + lane*16
    __builtin_amdgcn_global_load_lds(
        (const __attribute__((address_space(1))) unsigned int*)g,
        (__attribute__((address_space(3))) unsigned int*)l, 16, 0, 0);
}

// ---------------------------------------------------------------------------
// Combined cast/pack kernel: blocks [0,6144) pack x|cond -> bf16 inp,
// blocks [6144,10240) cast weights -> bf16.
// ---------------------------------------------------------------------------
__global__ __launch_bounds__(256) void prep(const float* __restrict__ x,
                                            const float* __restrict__ cond,
                                            const float* __restrict__ w_in,
                                            const float* __restrict__ w_out,
                                            unsigned short* __restrict__ inp,
                                            unsigned short* __restrict__ wi_bf,
                                            unsigned short* __restrict__ wo_bf) {
    if (blockIdx.x < 6144) {
        int v = blockIdx.x * 256 + threadIdx.x;
        int m  = v >> 8;
        int d4 = v & 255;
        int bb = (m >= SEQ) ? 1 : 0;
        int s  = m - bb * SEQ;
        const float* src = (s < TIN)
            ? x    + ((size_t)(bb * TIN   + s)        ) * DM + d4 * 4
            : cond + ((size_t)(bb * TCOND + (s - TIN))) * DM + d4 * 4;
        float4 f = *(const float4*)src;
        ushort4 u;
        u.x = f2bf(f.x); u.y = f2bf(f.y); u.z = f2bf(f.z); u.w = f2bf(f.w);
        *(ushort4*)(inp + (size_t)v * 4) = u;
    } else {
        int v = (blockIdx.x - 6144) * 256 + threadIdx.x;   // 0..1048575
        const float* src; unsigned short* dst; int idx;
        if (v < 786432) { src = w_in;  dst = wi_bf; idx = v; }
        else            { src = w_out; dst = wo_bf; idx = v - 786432; }
        float4 f = *(const float4*)(src + (size_t)idx * 4);
        ushort4 u;
        u.x = f2bf(f.x); u.y = f2bf(f.y); u.z = f2bf(f.z); u.w = f2bf(f.w);
        *(ushort4*)(dst + (size_t)idx * 4) = u;
    }
}

// ---------------------------------------------------------------------------
// QKV GEMM, window-restricted: Q for all 6144 rows; K,V only for the 1024
// window rows per batch (mask depends only on key index -> other rows are
// never consumed). Window tiles are located via end_inds[b] read in-kernel
// (always inside one segment: e in [512,1024)).
// blockIdx.y: [0,48) q m-tiles | [48,64) k window-tiles | [64,80) v window-tiles
// blockIdx.x: 128-col tile within the component (8 tiles of DM=1024).
// 256 thr, tile 128x128, BK=32, dbuf single-barrier pipeline (R5 structure).
// K -> compact (b,h,kw,hd); V -> compact transposed (b,h,hd,kw), kw in [0,1024).
// ---------------------------------------------------------------------------
__global__ __launch_bounds__(256, 4) void gemm_qkv(
        const unsigned short* __restrict__ A, const unsigned short* __restrict__ Bt,
        const float* __restrict__ bias, const int* __restrict__ end_inds,
        unsigned short* __restrict__ q_ws, unsigned short* __restrict__ k_ws,
        unsigned short* __restrict__ vt_ws) {
    __shared__ unsigned short smem[2 * 8192];   // 2 bufs x (As 4096 | Bs 4096) = 32 KB
    const int K = 1024;
    const int tid  = threadIdx.x;
    const int wave = tid >> 6, lane = tid & 63;
    const int quad = lane >> 4, c16 = lane & 15;
    const int wr = wave >> 1, wc = wave & 1;
    const int yb = blockIdx.y;
    const int which = (yb < 48) ? 0 : ((yb < 64) ? 1 : 2);
    const int n0c = blockIdx.x * 128;            // col tile within component

    // locate this block's 128 A-rows
    int m0, batch = 0, jj = 0;
    if (which == 0) {
        m0 = yb * 128;
    } else {
        int j = yb - (which == 1 ? 48 : 64);     // 0..15
        batch = j >> 3; jj = j & 7;
        int e = end_inds[batch];
        int seg = (jj < 4) ? 0 : 1;
        int off = (jj & 3) * 128;
        m0 = batch * SEQ + seg * TIN + (e - WIN) + off;
    }

    const unsigned short* gA[2];
    const unsigned short* gB[2];
    int ldst[2];
#pragma unroll
    for (int i = 0; i < 2; i++) {
        int flat = i * 256 + tid;
        int pr = flat >> 2, cp = flat & 3;
        int gc = cp ^ ((pr >> 1) & 3);
        gA[i] = A  + (size_t)(m0 + pr) * K + (gc << 3);
        gB[i] = Bt + (size_t)(which * DM + n0c + pr) * K + (gc << 3);
        ldst[i] = (i * 256 + wave * 64) * 8;
    }

    floatx4 acc[4][4];
#pragma unroll
    for (int i = 0; i < 4; i++)
#pragma unroll
        for (int j = 0; j < 4; j++) acc[i][j] = (floatx4){0.f, 0.f, 0.f, 0.f};

    // prologue: stage tile 0 into buf 0
#pragma unroll
    for (int i = 0; i < 2; i++) {
        gl2lds16(gA[i], &smem[ldst[i]]);
        gl2lds16(gB[i], &smem[4096 + ldst[i]]);
    }

#pragma unroll 2
    for (int it = 0; it < 32; ++it) {
        __syncthreads();                          // drains prev DMA (covered by compute)
        if (it + 1 < 32) {
            int bo = ((it + 1) & 1) * 8192;
            int k0 = (it + 1) << 5;
#pragma unroll
            for (int i = 0; i < 2; i++) {
                gl2lds16(gA[i] + k0, &smem[bo + ldst[i]]);
                gl2lds16(gB[i] + k0, &smem[bo + 4096 + ldst[i]]);
            }
        }
        const unsigned short* As = &smem[(it & 1) * 8192];
        const unsigned short* Bs = As + 4096;
        bf16x8 af[4], bfr[4];
#pragma unroll
        for (int t = 0; t < 4; t++) {
            int ra = wr * 64 + t * 16 + c16;
            int rb = wc * 64 + t * 16 + c16;
            af[t]  = *(const bf16x8*)&As[ra * 32 + ((quad ^ ((ra >> 1) & 3)) << 3)];
            bfr[t] = *(const bf16x8*)&Bs[rb * 32 + ((quad ^ ((rb >> 1) & 3)) << 3)];
        }
#pragma unroll
        for (int mt = 0; mt < 4; mt++)
#pragma unroll
            for (int nt = 0; nt < 4; nt++)
                acc[mt][nt] = __builtin_amdgcn_mfma_f32_16x16x32_bf16(
                    af[mt], bfr[nt], acc[mt][nt], 0, 0, 0);
    }

    // Epilogues. C/D layout: col = lane&15, row = quad*4 + r  (m89/m91)
    const int h0 = n0c >> 6;             // first of the 2 heads this block covers
    if (which == 2) {
        // vt[(bh*64+hd)*1024 + kw]: lane's 4 acc are 4 consecutive kw -> uint2
#pragma unroll
        for (int mt = 0; mt < 4; mt++) {
            int kw = jj * 128 + wr * 64 + mt * 16 + quad * 4;
#pragma unroll
            for (int nt = 0; nt < 4; nt++) {
                int gn = n0c + wc * 64 + nt * 16 + c16;
                float bi = bias[2 * DM + gn];
                int h = gn >> 6, hd = gn & 63;
                uint2 w;
                w.x = pack2bf(acc[mt][nt][0] + bi, acc[mt][nt][1] + bi);
                w.y = pack2bf(acc[mt][nt][2] + bi, acc[mt][nt][3] + bi);
                *(uint2*)&vt_ws[((size_t)(batch * NH + h) * HDIM + hd) * KW + kw] = w;
            }
        }
    } else {
        // q (full, (b,h,s,64)) or k (compact, (b,h,kw,64)): LDS transpose
        unsigned short* dstb = (which == 0) ? q_ws : k_ws;
        const float qs = (which == 0) ? 0.125f : 1.0f;
        const int bofs = which * DM;
#pragma unroll
        for (int mt = 0; mt < 4; mt++) {
            __syncthreads();
#pragma unroll
            for (int nt = 0; nt < 4; nt++) {
                int col = wc * 64 + nt * 16 + c16;
                float bi = bias[bofs + n0c + col];
#pragma unroll
                for (int r = 0; r < 4; r++)
                    smem[(wr * 16 + quad * 4 + r) * 136 + col] =
                        f2bf((acc[mt][nt][r] + bi) * qs);
            }
            __syncthreads();
#pragma unroll
            for (int p = 0; p < 2; p++) {
                int flat = p * 256 + tid;
                int row = flat >> 4, seg = flat & 15;
                bf16x8 v = *(const bf16x8*)&smem[row * 136 + seg * 8];
                int ml = (row >> 4) * 64 + mt * 16 + (row & 15);   // 0..127 in tile
                int h = h0 + (seg >> 3);
                size_t ridx;
                if (which == 0) {
                    int m = m0 + ml;
                    int bb = (m >= SEQ) ? 1 : 0;
                    int s = m - bb * SEQ;
                    ridx = (size_t)(bb * NH + h) * SEQ + s;
                } else {
                    ridx = (size_t)(batch * NH + h) * KW + (jj * 128 + ml);
                }
                *(bf16x8*)&dstb[ridx * HDIM + (seg & 7) * 8] = v;
            }
        }
    }
}

// ---------------------------------------------------------------------------
// Output GEMM: out = O(6144,1024) * Wo(1024,1024)^T + b, fp32 out.
// Tile 64x128 (wave tile 32x64), 256 thr, BK=32 dbuf. Grid 8x96 = 768 blocks.
// ---------------------------------------------------------------------------
__global__ __launch_bounds__(256, 4) void gemm_out(
        const unsigned short* __restrict__ A, const unsigned short* __restrict__ Bt,
        const float* __restrict__ bias, float* __restrict__ outp) {
    __shared__ unsigned short smem[2 * 6144];   // 2 bufs x (As 2048 | Bs 4096) = 24 KB
    const int K = 1024;
    const int tid  = threadIdx.x;
    const int wave = tid >> 6, lane = tid & 63;
    const int quad = lane >> 4, c16 = lane & 15;
    const int wr = wave >> 1, wc = wave & 1;     // 2m x 2n wave grid
    const int m0 = blockIdx.y * 64, n0 = blockIdx.x * 128;

    const unsigned short* gA;
    int ldstA;
    {
        int pr = tid >> 2, cp = tid & 3;
        int gc = cp ^ ((pr >> 1) & 3);
        gA = A + (size_t)(m0 + pr) * K + (gc << 3);
        ldstA = wave * 64 * 8;
    }
    const unsigned short* gB[2];
    int ldstB[2];
#pragma unroll
    for (int i = 0; i < 2; i++) {
        int flat = i * 256 + tid;
        int pr = flat >> 2, cp = flat & 3;
        int gc = cp ^ ((pr >> 1) & 3);
        gB[i] = Bt + (size_t)(n0 + pr) * K + (gc << 3);
        ldstB[i] = 2048 + (i * 256 + wave * 64) * 8;
    }

    floatx4 acc[2][4];
#pragma unroll
    for (int i = 0; i < 2; i++)
#pragma unroll
        for (int j = 0; j < 4; j++) acc[i][j] = (floatx4){0.f, 0.f, 0.f, 0.f};

    gl2lds16(gA, &smem[ldstA]);
    gl2lds16(gB[0], &smem[ldstB[0]]);
    gl2lds16(gB[1], &smem[ldstB[1]]);

#pragma unroll 2
    for (int it = 0; it < 32; ++it) {
        __syncthreads();
        if (it + 1 < 32) {
            int bo = ((it + 1) & 1) * 6144;
            int k0 = (it + 1) << 5;
            gl2lds16(gA + k0, &smem[bo + ldstA]);
            gl2lds16(gB[0] + k0, &smem[bo + ldstB[0]]);
            gl2lds16(gB[1] + k0, &smem[bo + ldstB[1]]);
        }
        const unsigned short* As = &smem[(it & 1) * 6144];
        const unsigned short* Bs = As + 2048;
        bf16x8 af[2], bfr[4];
#pragma unroll
        for (int t = 0; t < 2; t++) {
            int ra = wr * 32 + t * 16 + c16;
            af[t] = *(const bf16x8*)&As[ra * 32 + ((quad ^ ((ra >> 1) & 3)) << 3)];
        }
#pragma unroll
        for (int t = 0; t < 4; t++) {
            int rb = wc * 64 + t * 16 + c16;
            bfr[t] = *(const bf16x8*)&Bs[rb * 32 + ((quad ^ ((rb >> 1) & 3)) << 3)];
        }
#pragma unroll
        for (int mt = 0; mt < 2; mt++)
#pragma unroll
            for (int nt = 0; nt < 4; nt++)
                acc[mt][nt] = __builtin_amdgcn_mfma_f32_16x16x32_bf16(
                    af[mt], bfr[nt], acc[mt][nt], 0, 0, 0);
    }

    // fp32 out via LDS transpose -> coalesced float4 stores
    float* smf = (float*)smem;
#pragma unroll
    for (int mt = 0; mt < 2; mt++) {
        __syncthreads();
#pragma unroll
        for (int nt = 0; nt < 4; nt++) {
            int col = wc * 64 + nt * 16 + c16;
            float bi = bias[n0 + col];
#pragma unroll
            for (int r = 0; r < 4; r++)
                smf[(wr * 16 + quad * 4 + r) * 132 + col] = acc[mt][nt][r] + bi;
        }
        __syncthreads();
#pragma unroll
        for (int p = 0; p < 4; p++) {
            int flat = p * 256 + tid;
            int row = flat >> 5, seg = flat & 31;
            float4 v = *(const float4*)&smf[row * 132 + seg * 4];
            int m = m0 + (row >> 4) * 32 + mt * 16 + (row & 15);
            *(float4*)&outp[(size_t)m * DM + n0 + seg * 4] = v;
        }
    }
}

// ---------------------------------------------------------------------------
// Flash attention over compact window K/V: kw in [0,1024), no e-dependence.
// S^T = K*Q^T, 64-key dbuf chunks (32 KB LDS), 2 q-tiles/wave (128 q/block).
// Q: (B,H,S,64) bf16 (pre-scaled 1/8). Kc: (B,H,1024,64). Vtc: (B,H,64,1024).
// ---------------------------------------------------------------------------
__global__ __launch_bounds__(256, 4) void attn_kernel(
        const unsigned short* __restrict__ Q, const unsigned short* __restrict__ Kc,
        const unsigned short* __restrict__ Vtc,
        unsigned short* __restrict__ O) {
    __shared__ unsigned short smem[2 * 8192];   // 2 bufs x (Ks 4096 | Vs 4096) = 32 KB

    const int tid  = threadIdx.x;
    const int wave = tid >> 6, lane = tid & 63;
    const int quad = lane >> 4, c16 = lane & 15;
    const int qt = blockIdx.x, h = blockIdx.y, b = blockIdx.z;
    const int bh = b * NH + h;
    const int qbase = qt * 128 + wave * 32;

    const unsigned short* Qp = Q + ((size_t)bh * SEQ + qbase) * HDIM;
    bf16x8 bq[2][2];
#pragma unroll
    for (int qi = 0; qi < 2; qi++)
#pragma unroll
        for (int kk = 0; kk < 2; kk++)
            bq[qi][kk] = *(const bf16x8*)&Qp[(qi * 16 + c16) * HDIM + kk * 32 + quad * 8];

    float l_run[2] = {0.f, 0.f};
    floatx4 accO[2][4];
#pragma unroll
    for (int qi = 0; qi < 2; qi++)
#pragma unroll
        for (int t = 0; t < 4; t++) accO[qi][t] = (floatx4){0.f, 0.f, 0.f, 0.f};

    // staging geometry: K chunk 64 rows (key-permuted) x 64 hd; V 64 hd x 64 kw
    int k_src[2], v_src[2], dst_off[2];
#pragma unroll
    for (int i = 0; i < 2; i++) {
        int flat = i * 256 + tid;
        int pr = flat >> 3, cp = flat & 7;           // pr 0..63
        int m5 = pr & 31;
        int kl = (pr & ~31) + (((m5 & 15) >> 2) << 3) + (m5 & 3) + ((m5 >> 4) << 2);
        k_src[i] = kl * HDIM + ((cp ^ (pr & 7)) << 3);
        v_src[i] = pr * KW + ((cp ^ (pr & 7)) << 3);
        dst_off[i] = (i * 256 + wave * 64) * 8;
    }

    const unsigned short* Kbase = Kc  + (size_t)bh * KW * HDIM;
    const unsigned short* Vbase = Vtc + (size_t)bh * HDIM * KW;

    // prologue: stage chunk 0 into buf 0
#pragma unroll
    for (int i = 0; i < 2; i++) {
        gl2lds16(Kbase + k_src[i], &smem[dst_off[i]]);
        gl2lds16(Vbase + v_src[i], &smem[4096 + dst_off[i]]);
    }

    for (int ch = 0; ch < 16; ch++) {
        __syncthreads();
        if (ch + 1 < 16) {
            int bo = ((ch + 1) & 1) * 8192;
            int s0 = (ch + 1) * 64;
#pragma unroll
            for (int i = 0; i < 2; i++) {
                gl2lds16(Kbase + (size_t)s0 * HDIM + k_src[i], &smem[bo + dst_off[i]]);
                gl2lds16(Vbase + s0 + v_src[i], &smem[bo + 4096 + dst_off[i]]);
            }
        }
        const unsigned short* Ks = &smem[(ch & 1) * 8192];
        const unsigned short* Vs = Ks + 4096;

#pragma unroll
        for (int u = 0; u < 2; u++) {               // 32-key blocks
            unsigned int pb[2][4];                  // P^T B-frags (8 bf16 per qi)
#pragma unroll
            for (int sub = 0; sub < 2; sub++) {
                int prow = u * 32 + sub * 16 + c16;
                int sw = c16 & 7;
                bf16x8 ka0 = *(const bf16x8*)&Ks[prow * 64 + (( quad      ^ sw) << 3)];
                bf16x8 ka1 = *(const bf16x8*)&Ks[prow * 64 + (((quad + 4) ^ sw) << 3)];
#pragma unroll
                for (int qi = 0; qi < 2; qi++) {
                    floatx4 z = (floatx4){0.f, 0.f, 0.f, 0.f};
                    z = __builtin_amdgcn_mfma_f32_16x16x32_bf16(ka0, bq[qi][0], z, 0, 0, 0);
                    z = __builtin_amdgcn_mfma_f32_16x16x32_bf16(ka1, bq[qi][1], z, 0, 0, 0);
                    float p0 = __expf(z[0]), p1 = __expf(z[1]);
                    float p2 = __expf(z[2]), p3 = __expf(z[3]);
                    l_run[qi] += (p0 + p1) + (p2 + p3);
                    pb[qi][sub * 2 + 0] = pack2bf(p0, p1);
                    pb[qi][sub * 2 + 1] = pack2bf(p2, p3);
                }
            }
#pragma unroll
            for (int t = 0; t < 4; t++) {
                int vrow = t * 16 + c16;
                bf16x8 va = *(const bf16x8*)&Vs[vrow * 64 +
                                                (((u * 4 + quad) ^ (vrow & 7)) << 3)];
#pragma unroll
                for (int qi = 0; qi < 2; qi++)
                    accO[qi][t] = __builtin_amdgcn_mfma_f32_16x16x32_bf16(
                        va, *(const bf16x8*)&pb[qi][0], accO[qi][t], 0, 0, 0);
            }
        }
    }

    float inv[2];
#pragma unroll
    for (int qi = 0; qi < 2; qi++) {
        float l = l_run[qi];
        l += __shfl_xor(l, 16, 64);
        l += __shfl_xor(l, 32, 64);
        inv[qi] = 1.f / l;
    }

    // epilogue: transpose O^T -> O via LDS (padded stride 72), coalesced stores
    __syncthreads();
    unsigned short* Os = smem + wave * (32 * 72);
#pragma unroll
    for (int qi = 0; qi < 2; qi++)
#pragma unroll
        for (int t = 0; t < 4; t++) {
            uint2 w;
            w.x = pack2bf(accO[qi][t][0] * inv[qi], accO[qi][t][1] * inv[qi]);
            w.y = pack2bf(accO[qi][t][2] * inv[qi], accO[qi][t][3] * inv[qi]);
            *(uint2*)&Os[(qi * 16 + c16) * 72 + t * 16 + quad * 4] = w;
        }
    __syncthreads();
#pragma unroll
    for (int pass = 0; pass < 4; pass++) {
        int rq = pass * 8 + (lane >> 3);
        int part = lane & 7;
        bf16x8 v = *(const bf16x8*)&Os[rq * 72 + part * 8];
        int s = qbase + rq;
        *(bf16x8*)&O[((size_t)b * SEQ + s) * DM + h * HDIM + part * 8] = v;
    }
}

// ---------------------------------------------------------------------------
extern "C" void kernel_launch(void* const* d_in, const int* in_sizes, int n_in,
                              void* d_out, int out_size, void* d_ws, size_t ws_size,
                              hipStream_t stream) {
    const float* x      = (const float*)d_in[0];
    const float* cond   = (const float*)d_in[1];
    const int*   e_inds = (const int*)d_in[2];
    const float* w_in   = (const float*)d_in[3];
    const float* b_in   = (const float*)d_in[4];
    const float* w_out  = (const float*)d_in[5];
    const float* b_out  = (const float*)d_in[6];
    float* out = (float*)d_out;

    char* ws = (char*)d_ws;
    unsigned short* inp_bf = (unsigned short*)(ws);              // 12.6 MB
    unsigned short* wi_bf  = (unsigned short*)(ws + 12582912);   // 6.3 MB
    unsigned short* wo_bf  = (unsigned short*)(ws + 18874368);   // 2.1 MB
    unsigned short* q_ws   = (unsigned short*)(ws + 20971520);   // 12.6 MB (full)
    unsigned short* k_ws   = (unsigned short*)(ws + 33554432);   // 4 MB (compact)
    unsigned short* vt_ws  = (unsigned short*)(ws + 37748736);   // 4 MB (compact)
    unsigned short* o_bf   = inp_bf;   // alias: inp dead after GEMM1

    prep<<<10240, 256, 0, stream>>>(x, cond, w_in, w_out, inp_bf, wi_bf, wo_bf);
    gemm_qkv<<<dim3(8, 80), 256, 0, stream>>>(
        inp_bf, wi_bf, b_in, e_inds, q_ws, k_ws, vt_ws);
    attn_kernel<<<dim3(SEQ / 128, NH, NB), 256, 0, stream>>>(
        q_ws, k_ws, vt_ws, o_bf);
    gemm_out<<<dim3(DM / 128, MROWS / 64), 256, 0, stream>>>(
        o_bf, wo_bf, b_out, out);
}